// Round 5
// baseline (214.218 us; speedup 1.0000x reference)
//
#include <hip/hip_runtime.h>

// ROI Align on MI355X.
// input: (N=8, C=256, H=100, W=100) fp32 NCHW; rois (K,5); out (K,256,7,7) fp32.
//
// Round 5 (= round 4 with compile fix): gather was latency-bound (Occ 23%:
// 50KB LDS -> 3 blk/CU, 1000 blocks; VALU 21%, HBM 43%). Split each ROI into
// 2 channel-halves: 2000 blocks x 25KB LDS -> 6 blk/CU; lane owns 2 channels
// (float2, 512B/wave/corner, line-dense). Transpose had ~8-way LDS read
// conflicts (stride 68 -> bank stride 16); pad to 65 with scalar LDS ops ->
// <=2-way (free). Nontemporal final stores via native ext_vector float4
// (__builtin_nontemporal_store rejects HIP_vector_type).

typedef float nfloat4 __attribute__((ext_vector_type(4)));

constexpr int   OUT_H = 7;
constexpr int   OUT_W = 7;
constexpr int   NBINS = OUT_H * OUT_W;          // 49
constexpr float SPATIAL_SCALE = 0.25f;
constexpr int   SR = 2;
constexpr int   N_DIM = 8;
constexpr int   C_DIM = 256;
constexpr int   H_DIM = 100;
constexpr int   W_DIM = 100;
constexpr int   HW    = H_DIM * W_DIM;          // 10000
constexpr size_t NHWC_BYTES = (size_t)N_DIM * HW * C_DIM * sizeof(float); // 81,920,000

// ---------------- transpose: NCHW (n, 256, 10000) -> NHWC (n, 10000, 256) ---
// Tile 64ch x 64sp. Global float4 both sides; LDS scalar with stride 65:
// bank = (c + s) % 32 on both write and read -> <=2-way (free, m136).
constexpr int TP = 65;

__global__ __launch_bounds__(256) void nchw_to_nhwc(
    const float* __restrict__ in, float* __restrict__ out)
{
    __shared__ float tile[64 * TP];    // 16640 B
    int s0 = blockIdx.x * 64;
    int c0 = blockIdx.y * 64;
    int n  = blockIdx.z;

    int t   = threadIdx.x;
    int sl4 = (t & 15) * 4;            // spatial offset, float4
    int cq  = t >> 4;                  // 0..15

    #pragma unroll
    for (int r = 0; r < 4; ++r) {
        int cl = r * 16 + cq;
        int s  = s0 + sl4;
        const float* src = in + ((size_t)(n * C_DIM + c0 + cl) * HW + s);
        if (s + 3 < HW) {
            float4 v = *(const float4*)src;
            tile[cl * TP + sl4 + 0] = v.x;
            tile[cl * TP + sl4 + 1] = v.y;
            tile[cl * TP + sl4 + 2] = v.z;
            tile[cl * TP + sl4 + 3] = v.w;
        } else {
            #pragma unroll
            for (int i = 0; i < 4; ++i)
                tile[cl * TP + sl4 + i] = (s + i < HW) ? src[i] : 0.0f;
        }
    }
    __syncthreads();

    int cl4 = (t & 15) * 4;
    #pragma unroll
    for (int r = 0; r < 4; ++r) {
        int sl = r * 16 + cq;
        int s  = s0 + sl;
        if (s < HW) {
            float4 v;
            v.x = tile[(cl4 + 0) * TP + sl];
            v.y = tile[(cl4 + 1) * TP + sl];
            v.z = tile[(cl4 + 2) * TP + sl];
            v.w = tile[(cl4 + 3) * TP + sl];
            *(float4*)(out + ((size_t)n * HW + s) * C_DIM + c0 + cl4) = v;
        }
    }
}

// ---------------- gather: block = (ROI, channel-half), wave per bin ----------
// lane owns 2 channels of the 128-channel half; each corner = wave-coalesced
// 512B float2 load. Output half staged in LDS in exact (c,7,7) layout.
__global__ __launch_bounds__(256) void roi_gather_nhwc(
    const float* __restrict__ nhwc,
    const float* __restrict__ rois,
    float* __restrict__ out, int K)
{
    __shared__ float s_out[128 * NBINS];   // 25088 B

    int k = blockIdx.x;
    int h = blockIdx.y;                    // channel half: 0 or 1
    const float* r = rois + (size_t)k * 5;
    int   b  = (int)r[0];
    float x1 = r[1] * SPATIAL_SCALE;
    float y1 = r[2] * SPATIAL_SCALE;
    float x2 = r[3] * SPATIAL_SCALE;
    float y2 = r[4] * SPATIAL_SCALE;
    float roi_w = fmaxf(x2 - x1, 1.0f);
    float roi_h = fmaxf(y2 - y1, 1.0f);
    float bin_h = roi_h / (float)OUT_H;
    float bin_w = roi_w / (float)OUT_W;

    int wave = threadIdx.x >> 6;
    int lane = threadIdx.x & 63;
    int cb   = h * 128 + lane * 2;         // global channel base for this lane

    const float* img = nhwc + (size_t)b * HW * C_DIM;

    for (int bin = wave; bin < NBINS; bin += 4) {
        int oh = bin / OUT_W;
        int ow = bin - oh * OUT_W;

        float a0 = 0.f, a1 = 0.f;

        #pragma unroll
        for (int sy = 0; sy < SR; ++sy) {
            float gy = y1 + bin_h * (((float)(oh * SR + sy) + 0.5f) / (float)SR);
            bool  vy = (gy >= -1.0f) && (gy <= (float)H_DIM);
            float y  = fminf(fmaxf(gy, 0.0f), (float)(H_DIM - 1));
            int   yl = (int)floorf(y);
            float ly = y - (float)yl;
            int   yh = min(yl + 1, H_DIM - 1);

            #pragma unroll
            for (int sx = 0; sx < SR; ++sx) {
                float gx = x1 + bin_w * (((float)(ow * SR + sx) + 0.5f) / (float)SR);
                bool  vx = (gx >= -1.0f) && (gx <= (float)W_DIM);
                float x  = fminf(fmaxf(gx, 0.0f), (float)(W_DIM - 1));
                int   xl = (int)floorf(x);
                float lx = x - (float)xl;
                int   xh = min(xl + 1, W_DIM - 1);

                const float2 vll = *(const float2*)(img + (size_t)(yl * W_DIM + xl) * C_DIM + cb);
                const float2 vlh = *(const float2*)(img + (size_t)(yl * W_DIM + xh) * C_DIM + cb);
                const float2 vhl = *(const float2*)(img + (size_t)(yh * W_DIM + xl) * C_DIM + cb);
                const float2 vhh = *(const float2*)(img + (size_t)(yh * W_DIM + xh) * C_DIM + cb);

                float wll = (1.0f - ly) * (1.0f - lx);
                float wlh = (1.0f - ly) * lx;
                float whl = ly * (1.0f - lx);
                float whh = ly * lx;
                if (vy && vx) {
                    a0 += wll * vll.x + wlh * vlh.x + whl * vhl.x + whh * vhh.x;
                    a1 += wll * vll.y + wlh * vlh.y + whl * vhl.y + whh * vhh.y;
                }
            }
        }
        // local (c,7,7) layout; lane stride 98 floats -> 4-way conflict, tiny volume
        s_out[(lane * 2 + 0) * NBINS + bin] = a0 * 0.25f;
        s_out[(lane * 2 + 1) * NBINS + bin] = a1 * 0.25f;
    }
    __syncthreads();

    // coalesced nontemporal copy-out: 6272 floats = 1568 float4
    nfloat4* o4 = (nfloat4*)(out + (size_t)k * (C_DIM * NBINS) + (size_t)h * 128 * NBINS);
    const nfloat4* s4 = (const nfloat4*)s_out;
    for (int i = threadIdx.x; i < (128 * NBINS) / 4; i += 256)
        __builtin_nontemporal_store(s4[i], o4 + i);
}

// ---------------- fallback (round-0 baseline) if ws too small ---------------
__global__ __launch_bounds__(256) void roi_align_naive(
    const float* __restrict__ input, const float* __restrict__ rois,
    float* __restrict__ out, int K)
{
    int idx = blockIdx.x * blockDim.x + threadIdx.x;
    int total = K * C_DIM * OUT_H * OUT_W;
    if (idx >= total) return;
    int ow = idx % OUT_W;
    int oh = (idx / OUT_W) % OUT_H;
    int c  = (idx / (OUT_W * OUT_H)) % C_DIM;
    int k  = idx / (OUT_W * OUT_H * C_DIM);
    const float* r = rois + (size_t)k * 5;
    int   b  = (int)r[0];
    float x1 = r[1] * SPATIAL_SCALE, y1 = r[2] * SPATIAL_SCALE;
    float x2 = r[3] * SPATIAL_SCALE, y2 = r[4] * SPATIAL_SCALE;
    float roi_w = fmaxf(x2 - x1, 1.0f), roi_h = fmaxf(y2 - y1, 1.0f);
    float bin_h = roi_h / OUT_H, bin_w = roi_w / OUT_W;
    const float* inp = input + ((size_t)b * C_DIM + c) * HW;
    float acc = 0.0f;
    #pragma unroll
    for (int sy = 0; sy < SR; ++sy) {
        float gy = y1 + bin_h * (((float)(oh * SR + sy) + 0.5f) / SR);
        bool vy = (gy >= -1.0f) && (gy <= (float)H_DIM);
        float y = fminf(fmaxf(gy, 0.0f), (float)(H_DIM - 1));
        int yl = (int)floorf(y); float ly = y - yl; int yh = min(yl + 1, H_DIM - 1);
        #pragma unroll
        for (int sx = 0; sx < SR; ++sx) {
            float gx = x1 + bin_w * (((float)(ow * SR + sx) + 0.5f) / SR);
            bool vx = (gx >= -1.0f) && (gx <= (float)W_DIM);
            float x = fminf(fmaxf(gx, 0.0f), (float)(W_DIM - 1));
            int xl = (int)floorf(x); float lx = x - xl; int xh = min(xl + 1, W_DIM - 1);
            float v = (1.0f - ly) * ((1.0f - lx) * inp[yl * W_DIM + xl] + lx * inp[yl * W_DIM + xh])
                    + ly * ((1.0f - lx) * inp[yh * W_DIM + xl] + lx * inp[yh * W_DIM + xh]);
            if (vy && vx) acc += v;
        }
    }
    out[idx] = acc * 0.25f;
}

extern "C" void kernel_launch(void* const* d_in, const int* in_sizes, int n_in,
                              void* d_out, int out_size, void* d_ws, size_t ws_size,
                              hipStream_t stream) {
    const float* input = (const float*)d_in[0];
    const float* rois  = (const float*)d_in[1];
    float* out = (float*)d_out;
    int K = in_sizes[1] / 5;

    if (ws_size >= NHWC_BYTES) {
        float* nhwc = (float*)d_ws;
        dim3 tgrid((HW + 63) / 64, C_DIM / 64, N_DIM);   // 157 x 4 x 8
        nchw_to_nhwc<<<tgrid, 256, 0, stream>>>(input, nhwc);
        dim3 ggrid(K, 2);
        roi_gather_nhwc<<<ggrid, 256, 0, stream>>>(nhwc, rois, out, K);
    } else {
        int total = K * C_DIM * OUT_H * OUT_W;
        roi_align_naive<<<(total + 255) / 256, 256, 0, stream>>>(input, rois, out, K);
    }
}

// Round 6
// 185.431 us; speedup vs baseline: 1.1552x; 1.1552x over previous
//
#include <hip/hip_runtime.h>

// ROI Align on MI355X.
// input: (N=8, C=256, H=100, W=100) fp32 NCHW; rois (K,5); out (K,256,7,7) fp32.
//
// Round 6: occupancy knob proved dead (23%->48%, gather time identical 81us,
// FETCH 219MB for a 78MB array, HBM 43%) -> gather is bytes/transaction-bound.
// Halve the bytes: stage NHWC as bf16 (39MB). Gather: one block per ROI, lane
// owns 4 bf16 channels (8B uint2 load = 512B/wave/corner), unpack via shift,
// fp32 accumulate. absmax expected ~0.02 vs threshold 0.066.

typedef float nfloat4 __attribute__((ext_vector_type(4)));

constexpr int   OUT_H = 7;
constexpr int   OUT_W = 7;
constexpr int   NBINS = OUT_H * OUT_W;          // 49
constexpr float SPATIAL_SCALE = 0.25f;
constexpr int   SR = 2;
constexpr int   N_DIM = 8;
constexpr int   C_DIM = 256;
constexpr int   H_DIM = 100;
constexpr int   W_DIM = 100;
constexpr int   HW    = H_DIM * W_DIM;          // 10000
constexpr size_t NHWC_BF16_BYTES = (size_t)N_DIM * HW * C_DIM * 2; // 40,960,000

__device__ inline unsigned short f2bf_rne(float f) {
    unsigned u = __float_as_uint(f);
    u += 0x7fffu + ((u >> 16) & 1u);    // round-to-nearest-even
    return (unsigned short)(u >> 16);
}

// ---------------- transpose+cast: NCHW fp32 -> NHWC bf16 --------------------
// Tile 64ch x 64sp. Global float4 in / ushort4 out; LDS fp32 stride 65
// (bank = (c+s)%32 both sides -> <=2-way, free).
constexpr int TP = 65;

__global__ __launch_bounds__(256) void nchw_to_nhwc_bf16(
    const float* __restrict__ in, unsigned short* __restrict__ out)
{
    __shared__ float tile[64 * TP];    // 16640 B
    int s0 = blockIdx.x * 64;
    int c0 = blockIdx.y * 64;
    int n  = blockIdx.z;

    int t   = threadIdx.x;
    int sl4 = (t & 15) * 4;
    int cq  = t >> 4;                  // 0..15

    #pragma unroll
    for (int r = 0; r < 4; ++r) {
        int cl = r * 16 + cq;
        int s  = s0 + sl4;
        const float* src = in + ((size_t)(n * C_DIM + c0 + cl) * HW + s);
        if (s + 3 < HW) {
            float4 v = *(const float4*)src;
            tile[cl * TP + sl4 + 0] = v.x;
            tile[cl * TP + sl4 + 1] = v.y;
            tile[cl * TP + sl4 + 2] = v.z;
            tile[cl * TP + sl4 + 3] = v.w;
        } else {
            #pragma unroll
            for (int i = 0; i < 4; ++i)
                tile[cl * TP + sl4 + i] = (s + i < HW) ? src[i] : 0.0f;
        }
    }
    __syncthreads();

    int cl4 = (t & 15) * 4;
    #pragma unroll
    for (int r = 0; r < 4; ++r) {
        int sl = r * 16 + cq;
        int s  = s0 + sl;
        if (s < HW) {
            ushort4 h;
            h.x = f2bf_rne(tile[(cl4 + 0) * TP + sl]);
            h.y = f2bf_rne(tile[(cl4 + 1) * TP + sl]);
            h.z = f2bf_rne(tile[(cl4 + 2) * TP + sl]);
            h.w = f2bf_rne(tile[(cl4 + 3) * TP + sl]);
            *(ushort4*)(out + ((size_t)n * HW + s) * C_DIM + c0 + cl4) = h;
        }
    }
}

// ---------------- gather: block per ROI, wave per bin, lane = 4 bf16 ch ------
__global__ __launch_bounds__(256) void roi_gather_nhwc_bf16(
    const unsigned short* __restrict__ nhwc,
    const float* __restrict__ rois,
    float* __restrict__ out, int K)
{
    __shared__ float s_out[C_DIM * NBINS];   // 50176 B

    int k = blockIdx.x;
    const float* r = rois + (size_t)k * 5;
    int   b  = (int)r[0];
    float x1 = r[1] * SPATIAL_SCALE;
    float y1 = r[2] * SPATIAL_SCALE;
    float x2 = r[3] * SPATIAL_SCALE;
    float y2 = r[4] * SPATIAL_SCALE;
    float roi_w = fmaxf(x2 - x1, 1.0f);
    float roi_h = fmaxf(y2 - y1, 1.0f);
    float bin_h = roi_h / (float)OUT_H;
    float bin_w = roi_w / (float)OUT_W;

    int wave = threadIdx.x >> 6;
    int lane = threadIdx.x & 63;
    int cb   = lane * 4;                     // channel base (elements)

    const unsigned short* img = nhwc + (size_t)b * HW * C_DIM;

    for (int bin = wave; bin < NBINS; bin += 4) {
        int oh = bin / OUT_W;
        int ow = bin - oh * OUT_W;

        float2 a01 = {0.f, 0.f}, a23 = {0.f, 0.f};

        #pragma unroll
        for (int sy = 0; sy < SR; ++sy) {
            float gy = y1 + bin_h * (((float)(oh * SR + sy) + 0.5f) / (float)SR);
            bool  vy = (gy >= -1.0f) && (gy <= (float)H_DIM);
            float y  = fminf(fmaxf(gy, 0.0f), (float)(H_DIM - 1));
            int   yl = (int)floorf(y);
            float ly = y - (float)yl;
            int   yh = min(yl + 1, H_DIM - 1);

            #pragma unroll
            for (int sx = 0; sx < SR; ++sx) {
                float gx = x1 + bin_w * (((float)(ow * SR + sx) + 0.5f) / (float)SR);
                bool  vx = (gx >= -1.0f) && (gx <= (float)W_DIM);
                float x  = fminf(fmaxf(gx, 0.0f), (float)(W_DIM - 1));
                int   xl = (int)floorf(x);
                float lx = x - (float)xl;
                int   xh = min(xl + 1, W_DIM - 1);

                const uint2 qll = *(const uint2*)(img + (size_t)(yl * W_DIM + xl) * C_DIM + cb);
                const uint2 qlh = *(const uint2*)(img + (size_t)(yl * W_DIM + xh) * C_DIM + cb);
                const uint2 qhl = *(const uint2*)(img + (size_t)(yh * W_DIM + xl) * C_DIM + cb);
                const uint2 qhh = *(const uint2*)(img + (size_t)(yh * W_DIM + xh) * C_DIM + cb);

                float wll = (1.0f - ly) * (1.0f - lx);
                float wlh = (1.0f - ly) * lx;
                float whl = ly * (1.0f - lx);
                float whh = ly * lx;

                if (vy && vx) {
                    // bf16 pair -> 2 fp32: low = v<<16, high = v & 0xffff0000
                    #define ACC2(acc, q, w) { \
                        float lo = __uint_as_float((q) << 16); \
                        float hi = __uint_as_float((q) & 0xffff0000u); \
                        acc.x = fmaf((w), lo, acc.x); \
                        acc.y = fmaf((w), hi, acc.y); }
                    ACC2(a01, qll.x, wll) ACC2(a23, qll.y, wll)
                    ACC2(a01, qlh.x, wlh) ACC2(a23, qlh.y, wlh)
                    ACC2(a01, qhl.x, whl) ACC2(a23, qhl.y, whl)
                    ACC2(a01, qhh.x, whh) ACC2(a23, qhh.y, whh)
                    #undef ACC2
                }
            }
        }
        s_out[(cb + 0) * NBINS + bin] = a01.x * 0.25f;
        s_out[(cb + 1) * NBINS + bin] = a01.y * 0.25f;
        s_out[(cb + 2) * NBINS + bin] = a23.x * 0.25f;
        s_out[(cb + 3) * NBINS + bin] = a23.y * 0.25f;
    }
    __syncthreads();

    // coalesced nontemporal copy-out: 12544 floats = 3136 float4
    nfloat4* o4 = (nfloat4*)(out + (size_t)k * (C_DIM * NBINS));
    const nfloat4* s4 = (const nfloat4*)s_out;
    for (int i = threadIdx.x; i < (C_DIM * NBINS) / 4; i += 256)
        __builtin_nontemporal_store(s4[i], o4 + i);
}

// ---------------- fallback (round-0 baseline) if ws too small ---------------
__global__ __launch_bounds__(256) void roi_align_naive(
    const float* __restrict__ input, const float* __restrict__ rois,
    float* __restrict__ out, int K)
{
    int idx = blockIdx.x * blockDim.x + threadIdx.x;
    int total = K * C_DIM * OUT_H * OUT_W;
    if (idx >= total) return;
    int ow = idx % OUT_W;
    int oh = (idx / OUT_W) % OUT_H;
    int c  = (idx / (OUT_W * OUT_H)) % C_DIM;
    int k  = idx / (OUT_W * OUT_H * C_DIM);
    const float* r = rois + (size_t)k * 5;
    int   b  = (int)r[0];
    float x1 = r[1] * SPATIAL_SCALE, y1 = r[2] * SPATIAL_SCALE;
    float x2 = r[3] * SPATIAL_SCALE, y2 = r[4] * SPATIAL_SCALE;
    float roi_w = fmaxf(x2 - x1, 1.0f), roi_h = fmaxf(y2 - y1, 1.0f);
    float bin_h = roi_h / OUT_H, bin_w = roi_w / OUT_W;
    const float* inp = input + ((size_t)b * C_DIM + c) * HW;
    float acc = 0.0f;
    #pragma unroll
    for (int sy = 0; sy < SR; ++sy) {
        float gy = y1 + bin_h * (((float)(oh * SR + sy) + 0.5f) / SR);
        bool vy = (gy >= -1.0f) && (gy <= (float)H_DIM);
        float y = fminf(fmaxf(gy, 0.0f), (float)(H_DIM - 1));
        int yl = (int)floorf(y); float ly = y - yl; int yh = min(yl + 1, H_DIM - 1);
        #pragma unroll
        for (int sx = 0; sx < SR; ++sx) {
            float gx = x1 + bin_w * (((float)(ow * SR + sx) + 0.5f) / SR);
            bool vx = (gx >= -1.0f) && (gx <= (float)W_DIM);
            float x = fminf(fmaxf(gx, 0.0f), (float)(W_DIM - 1));
            int xl = (int)floorf(x); float lx = x - xl; int xh = min(xl + 1, W_DIM - 1);
            float v = (1.0f - ly) * ((1.0f - lx) * inp[yl * W_DIM + xl] + lx * inp[yl * W_DIM + xh])
                    + ly * ((1.0f - lx) * inp[yh * W_DIM + xl] + lx * inp[yh * W_DIM + xh]);
            if (vy && vx) acc += v;
        }
    }
    out[idx] = acc * 0.25f;
}

extern "C" void kernel_launch(void* const* d_in, const int* in_sizes, int n_in,
                              void* d_out, int out_size, void* d_ws, size_t ws_size,
                              hipStream_t stream) {
    const float* input = (const float*)d_in[0];
    const float* rois  = (const float*)d_in[1];
    float* out = (float*)d_out;
    int K = in_sizes[1] / 5;

    if (ws_size >= NHWC_BF16_BYTES) {
        unsigned short* nhwc = (unsigned short*)d_ws;
        dim3 tgrid((HW + 63) / 64, C_DIM / 64, N_DIM);   // 157 x 4 x 8
        nchw_to_nhwc_bf16<<<tgrid, 256, 0, stream>>>(input, nhwc);
        roi_gather_nhwc_bf16<<<K, 256, 0, stream>>>(nhwc, rois, out, K);
    } else {
        int total = K * C_DIM * OUT_H * OUT_W;
        roi_align_naive<<<(total + 255) / 256, 256, 0, stream>>>(input, rois, out, K);
    }
}